// Round 7
// baseline (53.471 us; speedup 1.0000x reference)
//
#include <hip/hip_runtime.h>
#include <hip/hip_bf16.h>

#define N_NODES 100000
#define N_EDGES 1600000
#define D_FEAT  64
#define NWIN    (N_EDGES / 64)          // 25000 windows of 64 edges

// d_ws layout: [offsets pad-1KB][bf16 table][hw partials][tw partials]
#define OFF_WS_BYTES   ((((N_NODES + 1) * 4) + 1023) & ~1023)
#define BF16_WS_BYTES  ((size_t)N_NODES * D_FEAT * 2)    // 12.8 MB
#define HW_WS_BYTES    ((size_t)NWIN * D_FEAT * 4)       // 6.4 MB
#define OFFSET_BLOCKS  ((N_NODES + 1 + 255) / 256)
#define CONVERT_BLOCKS 2048

// ---------- prep: offsets (binary search, proven) + f32->bf16 convert ----------
__global__ __launch_bounds__(256) void prep_kernel(
        const float* __restrict__ feat,
        const int* __restrict__ seg_ids,
        int* __restrict__ offsets,
        ushort* __restrict__ fb) {
    int b = blockIdx.x;
    if (b < OFFSET_BLOCKS) {
        int n = b * 256 + threadIdx.x;
        if (n > N_NODES) return;
        int lo = 0, hi = N_EDGES;
        while (lo < hi) {
            int mid = (lo + hi) >> 1;
            if (seg_ids[mid] < n) lo = mid + 1; else hi = mid;
        }
        offsets[n] = lo;
    } else {
        const int total = N_NODES * D_FEAT / 4;
        int tid = (b - OFFSET_BLOCKS) * 256 + threadIdx.x;
        for (int i = tid; i < total; i += CONVERT_BLOCKS * 256) {
            float4 v = reinterpret_cast<const float4*>(feat)[i];
            uint ux = __float_as_uint(v.x), uy = __float_as_uint(v.y);
            uint uz = __float_as_uint(v.z), uw = __float_as_uint(v.w);
            ushort4 o;
            o.x = (ushort)((ux + 0x7fffu + ((ux >> 16) & 1u)) >> 16);
            o.y = (ushort)((uy + 0x7fffu + ((uy >> 16) & 1u)) >> 16);
            o.z = (ushort)((uz + 0x7fffu + ((uz >> 16) & 1u)) >> 16);
            o.w = (ushort)((uw + 0x7fffu + ((uw >> 16) & 1u)) >> 16);
            reinterpret_cast<ushort4*>(fb)[i] = o;
        }
    }
}

__device__ __forceinline__ void unpack8(uint4 u, float* f) {
    f[0] = __uint_as_float(u.x << 16);
    f[1] = __uint_as_float(u.x & 0xFFFF0000u);
    f[2] = __uint_as_float(u.y << 16);
    f[3] = __uint_as_float(u.y & 0xFFFF0000u);
    f[4] = __uint_as_float(u.z << 16);
    f[5] = __uint_as_float(u.z & 0xFFFF0000u);
    f[6] = __uint_as_float(u.w << 16);
    f[7] = __uint_as_float(u.w & 0xFFFF0000u);
}

// ---------- aggregate: wave-per-64-edge-window, 8 gathers in flight ----------
// lane = slot*8 + ch; slot's edges are 64w+8*slot .. +7 (contiguous);
// ch picks the 16B uint4 chunk of the 128B bf16 row.
// Load L gathers 8 rows (one per slot) -> 8 independent loads, all real work.
// Per-lane run-walk over its 8 contiguous edges; interior-complete runs are
// stored directly (sole writer). Per-slot head/tail partials -> LDS item list
// (16 items, edge-ordered); per-wave sequential merge emits each merged run to
// exactly one of: out (complete), hw[w] (head partial), tw[w] (tail partial).
// No atomics; every row written by exactly one thread-group -> deterministic.
__global__ __launch_bounds__(256) void aggregate_seg_kernel(
        const ushort* __restrict__ fb,
        const int* __restrict__ neigh_idx,
        const int* __restrict__ seg_ids,
        float* __restrict__ out,
        float* __restrict__ hw,
        float* __restrict__ tw) {
    __shared__ float s_val[4][16][64];
    __shared__ int   s_seg[4][16];
    __shared__ int   s_valid[4][16];

    int wid  = threadIdx.x >> 6;
    int w    = blockIdx.x * 4 + wid;        // grid is exactly NWIN/4 -> always valid
    int lane = threadIdx.x & 63;
    int slot = lane >> 3;
    int ch   = lane & 7;
    int base = w * 64;

    int my_idx = neigh_idx[base + lane];
    int my_seg = seg_ids[base + lane];
    int seg_prev = (w > 0)        ? seg_ids[base - 1]  : -1;
    int seg_next = (w < NWIN - 1) ? seg_ids[base + 64] : -1;

    int e0 = slot * 8;
    int n0 = __shfl(my_idx, e0 + 0);
    int n1 = __shfl(my_idx, e0 + 1);
    int n2 = __shfl(my_idx, e0 + 2);
    int n3 = __shfl(my_idx, e0 + 3);
    int n4 = __shfl(my_idx, e0 + 4);
    int n5 = __shfl(my_idx, e0 + 5);
    int n6 = __shfl(my_idx, e0 + 6);
    int n7 = __shfl(my_idx, e0 + 7);

    const uint4* tb = reinterpret_cast<const uint4*>(fb);
    uint4 w0 = tb[(size_t)n0 * 8 + ch];
    uint4 w1 = tb[(size_t)n1 * 8 + ch];
    uint4 w2 = tb[(size_t)n2 * 8 + ch];
    uint4 w3 = tb[(size_t)n3 * 8 + ch];
    uint4 w4 = tb[(size_t)n4 * 8 + ch];
    uint4 w5 = tb[(size_t)n5 * 8 + ch];
    uint4 w6 = tb[(size_t)n6 * 8 + ch];
    uint4 w7 = tb[(size_t)n7 * 8 + ch];

    int sg0 = __shfl(my_seg, e0 + 0);
    int sg1 = __shfl(my_seg, e0 + 1);
    int sg2 = __shfl(my_seg, e0 + 2);
    int sg3 = __shfl(my_seg, e0 + 3);
    int sg4 = __shfl(my_seg, e0 + 4);
    int sg5 = __shfl(my_seg, e0 + 5);
    int sg6 = __shfl(my_seg, e0 + 6);
    int sg7 = __shfl(my_seg, e0 + 7);

    float acc[8], Hs[8], t_[8];
    int curseg, runstart, hseg = -1;
    unpack8(w0, acc);
    curseg = sg0; runstart = 0;

#define STEP(WL, SGL, LNUM)                                                   \
    if (SGL == curseg) {                                                      \
        unpack8(WL, t_);                                                      \
        _Pragma("unroll") for (int j = 0; j < 8; ++j) acc[j] += t_[j];        \
    } else {                                                                  \
        if (runstart == 0) {                                                  \
            hseg = curseg;                                                    \
            _Pragma("unroll") for (int j = 0; j < 8; ++j) Hs[j] = acc[j];     \
        } else {                                                              \
            float4* orow = reinterpret_cast<float4*>(out + (size_t)curseg * 64); \
            orow[ch * 2]     = make_float4(acc[0], acc[1], acc[2], acc[3]);   \
            orow[ch * 2 + 1] = make_float4(acc[4], acc[5], acc[6], acc[7]);   \
        }                                                                     \
        unpack8(WL, acc); curseg = SGL; runstart = LNUM;                      \
    }

    STEP(w1, sg1, 1)
    STEP(w2, sg2, 2)
    STEP(w3, sg3, 3)
    STEP(w4, sg4, 4)
    STEP(w5, sg5, 5)
    STEP(w6, sg6, 6)
    STEP(w7, sg7, 7)
#undef STEP

    // store items: head at 2*slot, tail at 2*slot+1 (invalid if single run)
    float* item0 = &s_val[wid][2 * slot][0];
    float* item1 = &s_val[wid][2 * slot + 1][0];
    if (runstart == 0) {                       // single run: one item
        reinterpret_cast<float4*>(item0)[ch * 2]     = make_float4(acc[0], acc[1], acc[2], acc[3]);
        reinterpret_cast<float4*>(item0)[ch * 2 + 1] = make_float4(acc[4], acc[5], acc[6], acc[7]);
        if (ch == 0) {
            s_seg[wid][2 * slot] = curseg;
            s_valid[wid][2 * slot] = 1;
            s_valid[wid][2 * slot + 1] = 0;
        }
    } else {                                   // head item + tail item
        reinterpret_cast<float4*>(item0)[ch * 2]     = make_float4(Hs[0], Hs[1], Hs[2], Hs[3]);
        reinterpret_cast<float4*>(item0)[ch * 2 + 1] = make_float4(Hs[4], Hs[5], Hs[6], Hs[7]);
        reinterpret_cast<float4*>(item1)[ch * 2]     = make_float4(acc[0], acc[1], acc[2], acc[3]);
        reinterpret_cast<float4*>(item1)[ch * 2 + 1] = make_float4(acc[4], acc[5], acc[6], acc[7]);
        if (ch == 0) {
            s_seg[wid][2 * slot] = hseg;
            s_seg[wid][2 * slot + 1] = curseg;
            s_valid[wid][2 * slot] = 1;
            s_valid[wid][2 * slot + 1] = 1;
        }
    }
    __syncthreads();

    // merge: lane owns float `lane` of the 64-float row; items are edge-ordered
    int mseg = -1, startItem = -1;
    float macc = 0.f;
#define EMIT(SEG, VAL, TSTART, TEND)                                          \
    {                                                                         \
        if ((TSTART) && (SEG) == seg_prev)                                    \
            hw[(size_t)w * 64 + lane] = (VAL);                                \
        else if ((TEND) && (SEG) == seg_next)                                 \
            tw[(size_t)w * 64 + lane] = (VAL);                                \
        else                                                                  \
            out[(size_t)(SEG) * 64 + lane] = (VAL);                          \
    }
    for (int i = 0; i < 16; ++i) {
        if (!s_valid[wid][i]) continue;        // wave-uniform
        int sgi = s_seg[wid][i];
        float v = s_val[wid][i][lane];
        if (mseg < 0) { mseg = sgi; macc = v; startItem = i; }
        else if (sgi == mseg) { macc += v; }
        else {
            EMIT(mseg, macc, startItem == 0, false)
            mseg = sgi; macc = v; startItem = i;
        }
    }
    EMIT(mseg, macc, startItem == 0, true)
#undef EMIT
}

// ---------- cleanup: combine boundary partials + zero empty nodes ----------
#define BOUNDARY_BLOCKS ((NWIN - 1 + 3) / 4)
__global__ __launch_bounds__(256) void cleanup_kernel(
        const int* __restrict__ seg_ids,
        const int* __restrict__ offsets,
        const float* __restrict__ hw,
        const float* __restrict__ tw,
        float* __restrict__ out) {
    if (blockIdx.x < BOUNDARY_BLOCKS) {
        int b = blockIdx.x * 4 + (threadIdx.x >> 6) + 1;   // 1..NWIN-1
        if (b >= NWIN) return;
        int lane = threadIdx.x & 63;
        int sL = seg_ids[b * 64 - 1];
        int sR = seg_ids[b * 64];
        if (sL == sR)
            out[(size_t)sR * 64 + lane] =
                tw[(size_t)(b - 1) * 64 + lane] + hw[(size_t)b * 64 + lane];
    } else {
        int n = (blockIdx.x - BOUNDARY_BLOCKS) * 256 + threadIdx.x;
        if (n < N_NODES && offsets[n] == offsets[n + 1]) {
            float4 z = make_float4(0.f, 0.f, 0.f, 0.f);
            float4* orow = reinterpret_cast<float4*>(out + (size_t)n * 64);
            #pragma unroll
            for (int k = 0; k < 16; ++k) orow[k] = z;
        }
    }
}

// ---------- fallback (round-6 proven path) if ws is too small ----------
__global__ __launch_bounds__(256) void aggregate_bf16_kernel(
        const ushort* __restrict__ fb,
        const int* __restrict__ neigh_idx,
        const int* __restrict__ offsets,
        float* __restrict__ out) {
    int node = blockIdx.x * 4 + (threadIdx.x >> 6);
    if (node >= N_NODES) return;
    int lane = threadIdx.x & 63;
    int slot = lane >> 3;
    int ch   = lane & 7;
    int s = offsets[node];
    int e = offsets[node + 1];
    float a0[8], a1[8];
    #pragma unroll
    for (int k = 0; k < 8; ++k) { a0[k] = 0.f; a1[k] = 0.f; }
    for (int cb = s; cb < e; cb += 64) {
        int li = cb + lane;
        int ci = (li < e) ? li : (e - 1);
        int my_idx = neigh_idx[ci];
        int lim = e - cb; if (lim > 64) lim = 64;
        for (int p = 0; p < lim; p += 16) {
            int p0 = p + slot, p1 = p0 + 8;
            int q0 = (p0 < lim) ? p0 : (lim - 1);
            int q1 = (p1 < lim) ? p1 : (lim - 1);
            float m0 = (p0 < lim) ? 1.f : 0.f;
            float m1 = (p1 < lim) ? 1.f : 0.f;
            int n0 = __shfl(my_idx, q0);
            int n1 = __shfl(my_idx, q1);
            uint4 w0 = reinterpret_cast<const uint4*>(fb + (size_t)n0 * D_FEAT)[ch];
            uint4 w1 = reinterpret_cast<const uint4*>(fb + (size_t)n1 * D_FEAT)[ch];
            float f0[8], f1[8];
            unpack8(w0, f0); unpack8(w1, f1);
            #pragma unroll
            for (int j = 0; j < 8; ++j) { a0[j] = fmaf(m0, f0[j], a0[j]); a1[j] = fmaf(m1, f1[j], a1[j]); }
        }
    }
    float r[8];
    #pragma unroll
    for (int k = 0; k < 8; ++k) r[k] = a0[k] + a1[k];
    #pragma unroll
    for (int k = 0; k < 8; ++k) {
        r[k] += __shfl_xor(r[k], 8);
        r[k] += __shfl_xor(r[k], 16);
        r[k] += __shfl_xor(r[k], 32);
    }
    if (lane < 8) {
        float4* orow = reinterpret_cast<float4*>(out + (size_t)node * D_FEAT);
        orow[2 * ch]     = make_float4(r[0], r[1], r[2], r[3]);
        orow[2 * ch + 1] = make_float4(r[4], r[5], r[6], r[7]);
    }
}

__global__ __launch_bounds__(256) void aggregate_f32_kernel(
        const float* __restrict__ feat,
        const int* __restrict__ neigh_idx,
        const int* __restrict__ offsets,
        float* __restrict__ out) {
    int node  = blockIdx.x * 4 + (threadIdx.x >> 6);
    if (node >= N_NODES) return;
    int lane  = threadIdx.x & 63;
    int sub   = lane >> 4;
    int chunk = lane & 15;
    int s = offsets[node];
    int e = offsets[node + 1];
    float4 a0 = make_float4(0.f, 0.f, 0.f, 0.f);
    float4 a1 = make_float4(0.f, 0.f, 0.f, 0.f);
    for (int base = s; base < e; base += 8) {
        int i0 = base + sub, i1 = i0 + 4;
        int c0 = (i0 < e) ? i0 : (e - 1);
        int c1 = (i1 < e) ? i1 : (e - 1);
        float m0 = (i0 < e) ? 1.f : 0.f;
        float m1 = (i1 < e) ? 1.f : 0.f;
        int n0 = neigh_idx[c0], n1 = neigh_idx[c1];
        float4 v0 = reinterpret_cast<const float4*>(feat + (size_t)n0 * D_FEAT)[chunk];
        float4 v1 = reinterpret_cast<const float4*>(feat + (size_t)n1 * D_FEAT)[chunk];
        a0.x = fmaf(m0, v0.x, a0.x); a0.y = fmaf(m0, v0.y, a0.y);
        a0.z = fmaf(m0, v0.z, a0.z); a0.w = fmaf(m0, v0.w, a0.w);
        a1.x = fmaf(m1, v1.x, a1.x); a1.y = fmaf(m1, v1.y, a1.y);
        a1.z = fmaf(m1, v1.z, a1.z); a1.w = fmaf(m1, v1.w, a1.w);
    }
    float4 acc;
    acc.x = a0.x + a1.x; acc.y = a0.y + a1.y;
    acc.z = a0.z + a1.z; acc.w = a0.w + a1.w;
    acc.x += __shfl_xor(acc.x, 16); acc.y += __shfl_xor(acc.y, 16);
    acc.z += __shfl_xor(acc.z, 16); acc.w += __shfl_xor(acc.w, 16);
    acc.x += __shfl_xor(acc.x, 32); acc.y += __shfl_xor(acc.y, 32);
    acc.z += __shfl_xor(acc.z, 32); acc.w += __shfl_xor(acc.w, 32);
    if (lane < 16) {
        reinterpret_cast<float4*>(out + (size_t)node * D_FEAT)[chunk] = acc;
    }
}

extern "C" void kernel_launch(void* const* d_in, const int* in_sizes, int n_in,
                              void* d_out, int out_size, void* d_ws, size_t ws_size,
                              hipStream_t stream) {
    const float* features  = (const float*)d_in[0];
    const int*   neigh_idx = (const int*)d_in[1];
    const int*   seg_ids   = (const int*)d_in[2];
    float*       out       = (float*)d_out;
    char*        wsb       = (char*)d_ws;
    int*         offsets   = (int*)wsb;

    size_t need_seg  = (size_t)OFF_WS_BYTES + BF16_WS_BYTES + 2 * HW_WS_BYTES;
    size_t need_bf16 = (size_t)OFF_WS_BYTES + BF16_WS_BYTES;

    if (ws_size >= need_seg) {
        ushort* fb = (ushort*)(wsb + OFF_WS_BYTES);
        float*  hw = (float*)(wsb + OFF_WS_BYTES + BF16_WS_BYTES);
        float*  tw = hw + (size_t)NWIN * D_FEAT;
        prep_kernel<<<OFFSET_BLOCKS + CONVERT_BLOCKS, 256, 0, stream>>>(
            features, seg_ids, offsets, fb);
        aggregate_seg_kernel<<<NWIN / 4, 256, 0, stream>>>(
            fb, neigh_idx, seg_ids, out, hw, tw);
        cleanup_kernel<<<BOUNDARY_BLOCKS + (N_NODES + 255) / 256, 256, 0, stream>>>(
            seg_ids, offsets, hw, tw, out);
    } else if (ws_size >= need_bf16) {
        ushort* fb = (ushort*)(wsb + OFF_WS_BYTES);
        prep_kernel<<<OFFSET_BLOCKS + CONVERT_BLOCKS, 256, 0, stream>>>(
            features, seg_ids, offsets, fb);
        aggregate_bf16_kernel<<<(N_NODES + 3) / 4, 256, 0, stream>>>(
            fb, neigh_idx, offsets, out);
    } else {
        prep_kernel<<<OFFSET_BLOCKS, 256, 0, stream>>>(
            features, seg_ids, offsets, (ushort*)nullptr);
        aggregate_f32_kernel<<<(N_NODES + 3) / 4, 256, 0, stream>>>(
            features, neigh_idx, offsets, out);
    }
}